// Round 1
// baseline (549.762 us; speedup 1.0000x reference)
//
#include <hip/hip_runtime.h>
#include <hip/hip_bf16.h>

// ---------------------------------------------------------------------------
// Spatial_AttLayer on MI355X (gfx950), bf16 MFMA, fully fused main kernel.
//
// Shapes: feature [8,256,1024,25] f32, text_feature [1,512,1,25],
// Wq/Wk [512,512], Wv [64,256], Wo [256,512]. attn is data-independent of
// `feature` and identical over batch -> precompute [8][25][25] once.
//
// Main kernel per workgroup: n, 4 consecutive t's; columns col = t*32+vp
// (vp padded 25->32, pad kept zero). Chain:
//   Vm = Wv@F + bv        (MFMA, M=64  K=256 N=128)
//   Zh = Vm@attn[h]       (MFMA, M=64  K=32  N=128, per head)
//   Out = sum_h Wo_h@Zh + bo + F   (MFMA, M=256 K=64/head N=128)
// Residual+bias folded into GEMM3 accumulator init.
// ---------------------------------------------------------------------------

typedef __attribute__((ext_vector_type(8))) short short8;
typedef __attribute__((ext_vector_type(4))) float f4v;

static __device__ __forceinline__ unsigned short f2bf(float f) {
  union { float f; unsigned u; } v; v.f = f;
  unsigned r = v.u + 0x7fffu + ((v.u >> 16) & 1u);   // RNE
  return (unsigned short)(r >> 16);
}
static __device__ __forceinline__ float bf2f(unsigned short h) {
  union { unsigned u; float f; } v; v.u = ((unsigned)h) << 16;
  return v.f;
}

// ws layout (unsigned short units unless noted):
//   WvP   [64][264]        bf16 (pad cols 256..263 = 0)      16896 elems
//   WoP   [8][256][72]     bf16 (per-head image, pad k>=64=0) 147456 elems
//   attnP [8][32][40]      bf16 (B-layout [vp][u], zero-padded) 10240 elems
//   qkP   [2][8][64][25]   f32 (q then k)                    25600 floats

// ---------------------------------------------------------------------------
// Kernel 1a: q/k 1x1 conv (one dot per thread) + weight conversions.
__global__ void k_qk_conv(const float* __restrict__ tf,
                          const float* __restrict__ Wq, const float* __restrict__ bq,
                          const float* __restrict__ Wk, const float* __restrict__ bk,
                          const float* __restrict__ Wv, const float* __restrict__ Wo,
                          unsigned short* __restrict__ WvP,
                          unsigned short* __restrict__ WoP,
                          float* __restrict__ qkP)
{
  __shared__ float tfl[12800];
  const int b = blockIdx.x, tid = threadIdx.x;
  if (b < 100) {
    for (int i = tid; i < 12800; i += 256) tfl[i] = tf[i];
    __syncthreads();
    int idx = b * 256 + tid;                    // 0..25599
    int isK = idx >= 12800;
    int j = isK ? idx - 12800 : idx;
    int g = j / 25, u = j - 25 * g;             // g: 0..511
    const float* wrow = (isK ? Wk : Wq) + g * 512;
    float s = (isK ? bk : bq)[g];
    for (int i = 0; i < 512; ++i) s += wrow[i] * tfl[i * 25 + u];
    qkP[idx] = s;
  } else {
    int cb = b - 100;                           // 0..63
    for (int i = cb * 256 + tid; i < 16896; i += 64 * 256) {
      int c = i / 264, kk = i - 264 * c;
      WvP[i] = (kk < 256) ? f2bf(Wv[c * 256 + kk]) : (unsigned short)0;
    }
    for (int i = cb * 256 + tid; i < 147456; i += 64 * 256) {
      int hh = i / 18432, rr = i - 18432 * hh;
      int o = rr / 72, kk = rr - 72 * o;
      WoP[i] = (kk < 64) ? f2bf(Wo[o * 512 + hh * 64 + kk]) : (unsigned short)0;
    }
  }
}

// ---------------------------------------------------------------------------
// Kernel 1b: energy + softmax per head -> attnP (zero-padded B-layout).
__global__ void k_attn(const float* __restrict__ qkP,
                       unsigned short* __restrict__ attnP)
{
  __shared__ float ql[1600], kl[1600], attl[625];
  const int h = blockIdx.x, tid = threadIdx.x;
  for (int i = tid; i < 1600; i += 256) {
    ql[i] = qkP[h * 1600 + i];
    kl[i] = qkP[12800 + h * 1600 + i];
  }
  __syncthreads();
  if (tid < 25) {
    int u = tid;
    float e[25];
    float mx = -1e30f;
    #pragma unroll
    for (int v = 0; v < 25; ++v) {
      float s = 0.f;
      #pragma unroll
      for (int r = 0; r < 64; ++r) s += ql[r * 25 + u] * kl[r * 25 + v];
      s *= 0.125f;                              // 1/sqrt(64)
      e[v] = s;
      mx = fmaxf(mx, s);
    }
    float den = 0.f;
    #pragma unroll
    for (int v = 0; v < 25; ++v) { e[v] = __expf(e[v] - mx); den += e[v]; }
    float inv = 1.f / den;
    #pragma unroll
    for (int v = 0; v < 25; ++v) attl[u * 25 + v] = e[v] * inv;
  }
  __syncthreads();
  // attnP[h][vp][u] = attn[u][vp]; zero where u>=25 or vp>=25
  for (int i = tid; i < 1280; i += 256) {
    int vp = i / 40, u = i - 40 * vp;
    attnP[h * 1280 + i] =
        (vp < 25 && u < 25) ? f2bf(attl[u * 25 + vp]) : (unsigned short)0;
  }
}

// ---------------------------------------------------------------------------
// Main fused kernel. 512 threads (8 waves), 1 WG/CU (LDS 140288 B).
// LDS: Fl [128][264] @0 | Vl [64][136] @67584 | Zl [128][72] @84992
//      | Wl [256][72] @103424   (strides chosen for <=2-way bank aliasing)
__launch_bounds__(512, 2)
__global__ void k_main(const float* __restrict__ feature,
                       const float* __restrict__ bv,
                       const float* __restrict__ bo,
                       const unsigned short* __restrict__ WvP,
                       const unsigned short* __restrict__ WoP,
                       const unsigned short* __restrict__ attnP,
                       float* __restrict__ out)
{
  extern __shared__ char smem[];
  unsigned short* Fl = (unsigned short*)smem;
  unsigned short* Vl = (unsigned short*)(smem + 67584);
  unsigned short* Zl = (unsigned short*)(smem + 84992);
  unsigned short* Wl = (unsigned short*)(smem + 103424);

  const int tid  = threadIdx.x;
  const int wave = tid >> 6;
  const int lane = tid & 63;
  const int quad = lane >> 4;
  const int l16  = lane & 15;
  const int n  = blockIdx.x >> 8;
  const int tb = blockIdx.x & 255;
  const int t0 = tb * 4;

  // --- zero F region (vp pads must be exactly 0) ---
  {
    short8 z = {0, 0, 0, 0, 0, 0, 0, 0};
    short8* fz = (short8*)smem;
    for (int i = tid; i < 4224; i += 512) fz[i] = z;
  }
  __syncthreads();

  // --- stage F: fp32 -> bf16, Fl[col=(t*32+vp)][cin] ---
  {
    const int c = tid >> 1, p = tid & 1;
    const float4* src = reinterpret_cast<const float4*>(
        feature + ((size_t)(n * 256 + c) * 1024 + t0) * 25);
    for (int i = p; i < 25; i += 2) {
      float4 f = src[i];
      float vv[4] = {f.x, f.y, f.z, f.w};
      int j0 = 4 * i;
      #pragma unroll
      for (int e = 0; e < 4; ++e) {
        int j = j0 + e;
        int t = j / 25;
        int vp = j - 25 * t;
        Fl[(t * 32 + vp) * 264 + c] = f2bf(vv[e]);
      }
    }
  }
  __syncthreads();

  const int wm = wave >> 1, wn = wave & 1;   // GEMM3 tiling: 4x2 wave grid

  // --- GEMM3 accumulators, init with bias + residual (C/D layout:
  //     row = quad*4+reg, col = l16 within each 16x16 tile) ---
  f4v acc[4][4];
  #pragma unroll
  for (int mi = 0; mi < 4; ++mi) {
    #pragma unroll
    for (int r = 0; r < 4; ++r) {
      int o = wm * 64 + mi * 16 + quad * 4 + r;
      float bor = bo[o];
      #pragma unroll
      for (int ni = 0; ni < 4; ++ni) {
        int colb = wn * 64 + ni * 16 + l16;
        acc[mi][ni][r] = bor + bf2f(Fl[colb * 264 + o]);
      }
    }
  }

  // --- GEMM1: Vm = Wv@F + bv. Wave w: Mtile=w&3, Ntiles 4*(w>>2).. ---
  {
    const int mt1 = wave & 3, nh1 = wave >> 2;
    f4v accv[4];
    #pragma unroll
    for (int ni = 0; ni < 4; ++ni) {
      #pragma unroll
      for (int r = 0; r < 4; ++r) accv[ni][r] = bv[mt1 * 16 + quad * 4 + r];
    }
    #pragma unroll
    for (int ks = 0; ks < 8; ++ks) {
      short8 a = *reinterpret_cast<const short8*>(
          WvP + (mt1 * 16 + l16) * 264 + ks * 32 + quad * 8);
      #pragma unroll
      for (int ni = 0; ni < 4; ++ni) {
        int colb = (4 * nh1 + ni) * 16 + l16;
        short8 b = *reinterpret_cast<const short8*>(
            &Fl[colb * 264 + ks * 32 + quad * 8]);
        accv[ni] = __builtin_amdgcn_mfma_f32_16x16x32_bf16(a, b, accv[ni], 0, 0, 0);
      }
    }
    #pragma unroll
    for (int ni = 0; ni < 4; ++ni) {
      int colb = (4 * nh1 + ni) * 16 + l16;
      #pragma unroll
      for (int r = 0; r < 4; ++r) {
        int c = mt1 * 16 + quad * 4 + r;
        Vl[c * 136 + colb] = f2bf(accv[ni][r]);
      }
    }
  }
  __syncthreads();

  // --- head loop: {Wo_h prefetch || GEMM2} barrier {GEMM3} barrier ---
  #pragma unroll 1
  for (int h = 0; h < 8; ++h) {
    // (1) issue Wo_h global loads early (latency hidden behind GEMM2)
    const short8* wsrc = reinterpret_cast<const short8*>(WoP + h * 18432);
    short8 wo_stage[5];
    #pragma unroll
    for (int c2 = 0; c2 < 5; ++c2) {
      int i = tid + c2 * 512;
      if (i < 2304) wo_stage[c2] = wsrc[i];
    }

    // (2) GEMM2: Zh = Vm @ attn[h]. Wave w: t=w>>1, M-half=w&1.
    {
      const int t2 = wave >> 1, mh = wave & 1;
      f4v accz[2][2];
      #pragma unroll
      for (int m2 = 0; m2 < 2; ++m2) {
        #pragma unroll
        for (int n2 = 0; n2 < 2; ++n2) {
          f4v z = {0.f, 0.f, 0.f, 0.f};
          accz[m2][n2] = z;
        }
      }
      short8 bfrag[2];
      #pragma unroll
      for (int n2 = 0; n2 < 2; ++n2)
        bfrag[n2] = *reinterpret_cast<const short8*>(
            attnP + h * 1280 + (n2 * 16 + l16) * 40 + quad * 8);
      #pragma unroll
      for (int m2 = 0; m2 < 2; ++m2) {
        short8 a = *reinterpret_cast<const short8*>(
            &Vl[((2 * mh + m2) * 16 + l16) * 136 + t2 * 32 + quad * 8]);
        #pragma unroll
        for (int n2 = 0; n2 < 2; ++n2)
          accz[m2][n2] =
              __builtin_amdgcn_mfma_f32_16x16x32_bf16(a, bfrag[n2], accz[m2][n2], 0, 0, 0);
      }
      #pragma unroll
      for (int m2 = 0; m2 < 2; ++m2) {
        #pragma unroll
        for (int n2 = 0; n2 < 2; ++n2) {
          #pragma unroll
          for (int r = 0; r < 4; ++r) {
            int c = (2 * mh + m2) * 16 + quad * 4 + r;
            int colz = t2 * 32 + n2 * 16 + l16;
            Zl[colz * 72 + c] = f2bf(accz[m2][n2][r]);
          }
        }
      }
    }

    // (3) commit Wo_h to LDS
    {
      short8* wdst = reinterpret_cast<short8*>(Wl);
      #pragma unroll
      for (int c2 = 0; c2 < 5; ++c2) {
        int i = tid + c2 * 512;
        if (i < 2304) wdst[i] = wo_stage[c2];
      }
    }
    __syncthreads();

    // (4) GEMM3: acc += Wo_h @ Zh  (K=64, 2 k-steps)
    #pragma unroll
    for (int ks = 0; ks < 2; ++ks) {
      short8 afr[4], bfr[4];
      #pragma unroll
      for (int mi = 0; mi < 4; ++mi)
        afr[mi] = *reinterpret_cast<const short8*>(
            &Wl[(wm * 64 + mi * 16 + l16) * 72 + ks * 32 + quad * 8]);
      #pragma unroll
      for (int ni = 0; ni < 4; ++ni)
        bfr[ni] = *reinterpret_cast<const short8*>(
            &Zl[(wn * 64 + ni * 16 + l16) * 72 + ks * 32 + quad * 8]);
      #pragma unroll
      for (int mi = 0; mi < 4; ++mi) {
        #pragma unroll
        for (int ni = 0; ni < 4; ++ni)
          acc[mi][ni] =
              __builtin_amdgcn_mfma_f32_16x16x32_bf16(afr[mi], bfr[ni], acc[mi][ni], 0, 0, 0);
      }
    }
    __syncthreads();
  }

  // --- epilogue: store fp32, skip vp pads ---
  #pragma unroll
  for (int ni = 0; ni < 4; ++ni) {
    int colb = wn * 64 + ni * 16 + l16;
    int t = colb >> 5, vp = colb & 31;
    if (vp < 25) {
      #pragma unroll
      for (int mi = 0; mi < 4; ++mi) {
        #pragma unroll
        for (int r = 0; r < 4; ++r) {
          int o = wm * 64 + mi * 16 + quad * 4 + r;
          out[((size_t)(n * 256 + o) * 1024 + (t0 + t)) * 25 + vp] = acc[mi][ni][r];
        }
      }
    }
  }
}

// ---------------------------------------------------------------------------
extern "C" void kernel_launch(void* const* d_in, const int* in_sizes, int n_in,
                              void* d_out, int out_size, void* d_ws, size_t ws_size,
                              hipStream_t stream)
{
  const float* feature = (const float*)d_in[0];
  const float* tf      = (const float*)d_in[1];
  const float* Wq      = (const float*)d_in[2];
  const float* bq      = (const float*)d_in[3];
  const float* Wk      = (const float*)d_in[4];
  const float* bk      = (const float*)d_in[5];
  const float* Wv      = (const float*)d_in[6];
  const float* bv      = (const float*)d_in[7];
  const float* Wo      = (const float*)d_in[8];
  const float* bo      = (const float*)d_in[9];
  float* out = (float*)d_out;

  unsigned short* WvP   = (unsigned short*)d_ws;        // 16896
  unsigned short* WoP   = WvP + 16896;                  // 147456
  unsigned short* attnP = WoP + 147456;                 // 10240
  float* qkP = (float*)(attnP + 10240);                 // 25600 floats

  hipLaunchKernelGGL(k_qk_conv, dim3(164), dim3(256), 0, stream,
                     tf, Wq, bq, Wk, bk, Wv, Wo, WvP, WoP, qkP);
  hipLaunchKernelGGL(k_attn, dim3(8), dim3(256), 0, stream, qkP, attnP);

  hipFuncSetAttribute(reinterpret_cast<const void*>(&k_main),
                      hipFuncAttributeMaxDynamicSharedMemorySize, 140288);
  hipLaunchKernelGGL(k_main, dim3(2048), dim3(512), 140288, stream,
                     feature, bv, bo, WvP, WoP, attnP, out);
}